// Round 1
// baseline (754.815 us; speedup 1.0000x reference)
//
#include <hip/hip_runtime.h>
#include <hip/hip_bf16.h>
#include <math.h>

typedef __attribute__((ext_vector_type(4))) float f32x4;
typedef __attribute__((ext_vector_type(8))) short s16x8;

#define LOG2E 1.4426950408889634f
#define LN2f  0.6931471805599453f
#define INV_E 0.36787944117144233f

__device__ __forceinline__ short bfc(float x) {
  unsigned u = __float_as_uint(x);
  unsigned r = u + 0x7fffu + ((u >> 16) & 1u);   // RNE to bf16
  return (short)(r >> 16);
}

__device__ __forceinline__ unsigned pk2(float x, float y) {
  union { __hip_bfloat162 h; unsigned u; } c;
  c.h = __float22bfloat162_rn(make_float2(x, y));  // v_cvt_pk_bf16_f32
  return c.u;
}

__device__ __forceinline__ float bperm(float v, int byte_addr) {
  return __int_as_float(__builtin_amdgcn_ds_bpermute(byte_addr, __float_as_int(v)));
}

__device__ __forceinline__ float rdlane(float v, int lane) {
  return __int_as_float(__builtin_amdgcn_readlane(__float_as_int(v), lane));
}

__device__ __forceinline__ float pick9(int j, float a0, float a1, float a2,
                                       float a3, float a4, float a5, float a6,
                                       float a7, float a8) {
  float v = a0;
  if (j == 1) v = a1;
  if (j == 2) v = a2;
  if (j == 3) v = a3;
  if (j == 4) v = a4;
  if (j == 5) v = a5;
  if (j == 6) v = a6;
  if (j == 7) v = a7;
  if (j == 8) v = a8;
  return v;
}

// ---------------------------------------------------------------------------
// Kernel 0: W (V x D fp32) -> Wb (64 x D bf16), rows >= V zero-filled.
// ---------------------------------------------------------------------------
__global__ void conv_w(const float* __restrict__ W, short* __restrict__ Wb,
                       int V, int D) {
  int idx = blockIdx.x * blockDim.x + threadIdx.x;
  if (idx >= 64 * D) return;
  int row = idx / D, col = idx - row * D;
  Wb[idx] = (row < V) ? bfc(W[(size_t)row * D + col]) : (short)0;
}

// ---------------------------------------------------------------------------
// Fused kernel: producer/consumer overlap in ONE dispatch.
//   blocks [0, B)        : star-CTC DP consumer (1 wave; waves 1-3 return)
//   blocks [B, B+B*CPB)  : GEMM+softmax-exp producer; block j covers batch
//                          b = j%B, time-chunk c = j/B (t in [c*128,c*128+128)).
//                          t-major ordering so all batches' early chunks are
//                          produced first.
// Sync: flags[b*CPB+c] set with agent-scope RELEASE after the block's pt rows
// are stored (syncthreads first); consumer spins with agent-scope ACQUIRE
// (handles cross-XCD L2 non-coherence). Producers never wait -> no deadlock.
// ---------------------------------------------------------------------------
__global__ __launch_bounds__(256) void fused_gemm_star(
    const float* __restrict__ feat, const short* __restrict__ Wb,
    const float* __restrict__ bias, float* __restrict__ pt,
    int* __restrict__ flags,
    const int* __restrict__ targets, const int* __restrict__ in_len,
    const int* __restrict__ tgt_len, float* __restrict__ partial,
    int nrows, int D, int V, int T, int S, int B, int CPB) {

  if ((int)blockIdx.x >= B) {
    // ================= producer: GEMM + per-row exp table =================
    const int j = blockIdx.x - B;
    const int b = j % B;
    const int c = j / B;
    const int tc0 = c * 128;
    const int rlen = (T - tc0 < 128) ? (T - tc0) : 128;
    const int rowlim = b * T + tc0 + rlen;

    const int lane = threadIdx.x & 63;
    const int wave = threadIdx.x >> 6;
    const int m_lo = lane & 15;
    const int q = lane >> 4;
    const int rowbase = b * T + tc0 + wave * 32;

    int arow0 = rowbase + m_lo;
    int arow1 = rowbase + 16 + m_lo;
    if (arow0 >= nrows) arow0 = nrows - 1;       // clamp loads; stores guarded
    if (arow1 >= nrows) arow1 = nrows - 1;
    const float* Ap0 = feat + (size_t)arow0 * D + q * 8;
    const float* Ap1 = feat + (size_t)arow1 * D + q * 8;
    const short* Bp = Wb + (size_t)m_lo * D + q * 8;
    const size_t bstr = (size_t)16 * D;

    f32x4 acc[2][4];
    #pragma unroll
    for (int g = 0; g < 2; ++g)
      #pragma unroll
      for (int ni = 0; ni < 4; ++ni) acc[g][ni] = (f32x4){0.f, 0.f, 0.f, 0.f};

    float4 al0 = *(const float4*)(Ap0);
    float4 ah0 = *(const float4*)(Ap0 + 4);
    float4 al1 = *(const float4*)(Ap1);
    float4 ah1 = *(const float4*)(Ap1 + 4);
    s16x8 b0 = *(const s16x8*)(Bp);
    s16x8 b1 = *(const s16x8*)(Bp + bstr);
    s16x8 b2 = *(const s16x8*)(Bp + 2 * bstr);
    s16x8 b3 = *(const s16x8*)(Bp + 3 * bstr);

    for (int k0 = 0; k0 < D; k0 += 32) {
      const int kn = (k0 + 32 < D) ? (k0 + 32) : 0;  // dummy reload last iter
      const float* Ap0n = feat + (size_t)arow0 * D + kn + q * 8;
      const float* Ap1n = feat + (size_t)arow1 * D + kn + q * 8;
      const short* Bpn = Wb + (size_t)m_lo * D + kn + q * 8;
      float4 nal0 = *(const float4*)(Ap0n);
      float4 nah0 = *(const float4*)(Ap0n + 4);
      float4 nal1 = *(const float4*)(Ap1n);
      float4 nah1 = *(const float4*)(Ap1n + 4);
      s16x8 nb0 = *(const s16x8*)(Bpn);
      s16x8 nb1 = *(const s16x8*)(Bpn + bstr);
      s16x8 nb2 = *(const s16x8*)(Bpn + 2 * bstr);
      s16x8 nb3 = *(const s16x8*)(Bpn + 3 * bstr);

      union { s16x8 v; unsigned u[4]; } av0, av1;
      av0.u[0] = pk2(al0.x, al0.y); av0.u[1] = pk2(al0.z, al0.w);
      av0.u[2] = pk2(ah0.x, ah0.y); av0.u[3] = pk2(ah0.z, ah0.w);
      av1.u[0] = pk2(al1.x, al1.y); av1.u[1] = pk2(al1.z, al1.w);
      av1.u[2] = pk2(ah1.x, ah1.y); av1.u[3] = pk2(ah1.z, ah1.w);

      acc[0][0] = __builtin_amdgcn_mfma_f32_16x16x32_bf16(av0.v, b0, acc[0][0], 0, 0, 0);
      acc[0][1] = __builtin_amdgcn_mfma_f32_16x16x32_bf16(av0.v, b1, acc[0][1], 0, 0, 0);
      acc[0][2] = __builtin_amdgcn_mfma_f32_16x16x32_bf16(av0.v, b2, acc[0][2], 0, 0, 0);
      acc[0][3] = __builtin_amdgcn_mfma_f32_16x16x32_bf16(av0.v, b3, acc[0][3], 0, 0, 0);
      acc[1][0] = __builtin_amdgcn_mfma_f32_16x16x32_bf16(av1.v, b0, acc[1][0], 0, 0, 0);
      acc[1][1] = __builtin_amdgcn_mfma_f32_16x16x32_bf16(av1.v, b1, acc[1][1], 0, 0, 0);
      acc[1][2] = __builtin_amdgcn_mfma_f32_16x16x32_bf16(av1.v, b2, acc[1][2], 0, 0, 0);
      acc[1][3] = __builtin_amdgcn_mfma_f32_16x16x32_bf16(av1.v, b3, acc[1][3], 0, 0, 0);

      al0 = nal0; ah0 = nah0; al1 = nal1; ah1 = nah1;
      b0 = nb0; b1 = nb1; b2 = nb2; b3 = nb3;
    }

    float bias_v[4];
    #pragma unroll
    for (int ni = 0; ni < 4; ++ni) {
      int col = ni * 16 + m_lo;
      bias_v[ni] = (col < V) ? bias[col] : 0.f;
    }

    // C/D layout: col = lane&15, row = (lane>>4)*4 + reg   [m89-verified]
    #pragma unroll
    for (int g = 0; g < 2; ++g) {
      #pragma unroll
      for (int r = 0; r < 4; ++r) {
        int grow = rowbase + g * 16 + q * 4 + r;
        float lg[4];
        #pragma unroll
        for (int ni = 0; ni < 4; ++ni) {
          int col = ni * 16 + m_lo;
          lg[ni] = (col < V) ? (acc[g][ni][r] + bias_v[ni]) : -1e30f;
        }
        float m = fmaxf(fmaxf(lg[0], lg[1]), fmaxf(lg[2], lg[3]));
        #pragma unroll
        for (int off = 1; off < 16; off <<= 1) m = fmaxf(m, __shfl_xor(m, off));
        float p[4];
        #pragma unroll
        for (int ni = 0; ni < 4; ++ni) p[ni] = exp2f((lg[ni] - m) * LOG2E);
        float s = (p[0] + p[1]) + (p[2] + p[3]);
        #pragma unroll
        for (int off = 1; off < 16; off <<= 1) s += __shfl_xor(s, off);

        if (grow < rowlim) {
          float* orow = pt + (size_t)grow * 64;
          orow[m_lo] = p[0];
          orow[16 + m_lo] = p[1];
          orow[32 + m_lo] = p[2];
          if (m_lo < 8)       orow[48 + m_lo] = p[3];
          else if (m_lo == 8) orow[56] = logf(s);        // K_t (ln units)
          else if (m_lo == 9) orow[57] = s * INV_E;      // star~ emission
          else                orow[48 + m_lo] = 0.f;     // cols 58..63
        }
      }
    }

    __syncthreads();                 // all 4 waves' stores issued+drained
    if (threadIdx.x == 0)
      __hip_atomic_store(&flags[b * CPB + c], 1, __ATOMIC_RELEASE,
                         __HIP_MEMORY_SCOPE_AGENT);
    return;
  }

  // ================= consumer: star-CTC DP (1 wave / sequence) =============
  if (threadIdx.x >= 64) return;
  const int n = blockIdx.x;
  const int lane = threadIdx.x;
  const float* row = pt + (size_t)n * T * 64;
  const int len = in_len[n];
  const int tl = tgt_len[n];
  const int* tg = targets + (size_t)n * S;
  const int* fl = flags + n * CPB;

  int cdone = -1;
#define WAITC(cc)                                                            \
  do {                                                                       \
    int _c = (cc);                                                           \
    while (cdone < _c) {                                                     \
      if (__hip_atomic_load((int*)&fl[cdone + 1], __ATOMIC_ACQUIRE,          \
                            __HIP_MEMORY_SCOPE_AGENT))                       \
        ++cdone;                                                             \
      else                                                                   \
        __builtin_amdgcn_s_sleep(2);                                         \
    }                                                                        \
  } while (0)

  const int s0 = lane * 4;
  int lab1 = (s0     < S) ? tg[s0]     : 0;
  int lab3 = (s0 + 1 < S) ? tg[s0 + 1] : 0;
  int lab5 = (s0 + 2 < S) ? tg[s0 + 2] : 0;
  int lab7 = (s0 + 3 < S) ? tg[s0 + 3] : 0;
  int labm1 = __shfl_up(lab7, 1);                // label of state 8k-1
  int labm3 = __shfl_up(lab5, 1);                // label of state 8k-3
  const bool sk1 = (lane > 0) && (lab1 != labm1);
  const bool sk3 = (lab3 != lab1);
  const bool sk5 = (lab5 != lab3);
  const bool sk7 = (lab7 != lab5);
  const bool skm1 = (labm1 != labm3);
  const int ad1 = lab1 << 2, ad3 = lab3 << 2, ad5 = lab5 << 2, ad7 = lab7 << 2;
  const int adm1 = labm1 << 2;

  float a0 = 0, a1 = 0, a2 = 0, a3 = 0, a4 = 0, a5 = 0, a6 = 0, a7 = 0, a8 = 0;
  float m1 = 0.f, m2 = 0.f, m3 = 0.f;
  int eps = 0, eL = 0;
  bool act = (lane == 0);

#define ROWL(t) row[(size_t)(((t) < len) ? (t) : (len - 1)) * 64 + lane]

  WAITC(0);                                      // rows 0..8 live in chunk 0

  // t = 0
  float rc = row[lane];
  {
    float star = rdlane(rc, 57);
    float e1i = bperm(rc, ad1);
    if (lane == 0) { a0 = star; a1 = e1i; }
  }
  float ksum = rc;

  // prefetch ring: rows 1..8
  float rr0 = ROWL(1), rr1 = ROWL(2), rr2 = ROWL(3), rr3 = ROWL(4);
  float rr4 = ROWL(5), rr5 = ROWL(6), rr6 = ROWL(7), rr7 = ROWL(8);

  // emissions for first pair (t=1,2)
  float es0v = rdlane(rr0, 57);
  float e1a = bperm(rr0, ad1), e3a = bperm(rr0, ad3);
  float e5a = bperm(rr0, ad5), e7a = bperm(rr0, ad7);
  float em1a = bperm(rr0, adm1);
  float es1v = rdlane(rr1, 57);
  float e1b = bperm(rr1, ad1), e3b = bperm(rr1, ad3);
  float e5b = bperm(rr1, ad5), e7b = bperm(rr1, ad7);

#define RENORM()                                                             \
  do {                                                                       \
    float mx = fmaxf(fmaxf(fmaxf(a0, a1), fmaxf(a2, a3)),                    \
                     fmaxf(fmaxf(a4, a5), fmaxf(a6, a7)));                   \
    mx = fmaxf(mx, a8);                                                      \
    int e = (int)((__float_as_uint(mx) >> 23) & 255) - 126;                  \
    e = (act && mx > 0.f) ? e : 0;                                           \
    a0 = ldexpf(a0, -e); a1 = ldexpf(a1, -e); a2 = ldexpf(a2, -e);           \
    a3 = ldexpf(a3, -e); a4 = ldexpf(a4, -e); a5 = ldexpf(a5, -e);           \
    a6 = ldexpf(a6, -e); a7 = ldexpf(a7, -e); a8 = ldexpf(a8, -e);           \
    eps += e;                                                                \
  } while (0)

#define PAIR(C0, C1, N0, N1, P0, P1, DOREN)                                  \
  do {                                                                       \
    ksum += C0; ksum += C1;                                                  \
    if (!act) eps = eL;                                                      \
    bool inc = (lane != 0) &&                                                \
               ((m1 != 0.f) || (m2 != 0.f) || (m3 != 0.f));                  \
    int d = inc ? (eL - eps) : 0;                                            \
    if (__builtin_expect(d > 24, 0)) {            /* raise own frame */      \
      a0 = ldexpf(a0, -d); a1 = ldexpf(a1, -d); a2 = ldexpf(a2, -d);         \
      a3 = ldexpf(a3, -d); a4 = ldexpf(a4, -d); a5 = ldexpf(a5, -d);         \
      a6 = ldexpf(a6, -d); a7 = ldexpf(a7, -d); a8 = ldexpf(a8, -d);         \
      eps += d;                                   /* m stay in frame eL */   \
    } else {                                                                 \
      m1 = ldexpf(m1, d); m2 = ldexpf(m2, d); m3 = ldexpf(m3, d);            \
    }                                                                        \
    act = act || (m1 != 0.f) || (m2 != 0.f) || (m3 != 0.f);                  \
    /* sub-step 1 (in-place top-down; uses old lower states) */              \
    a8 = (a8 + a7) * es0v;                                                   \
    a7 = (a7 + a6 + (sk7 ? a5 : 0.f)) * e7a;                                 \
    a6 = (a6 + a5) * es0v;                                                   \
    a5 = (a5 + a4 + (sk5 ? a3 : 0.f)) * e5a;                                 \
    a4 = (a4 + a3) * es0v;                                                   \
    a3 = (a3 + a2 + (sk3 ? a1 : 0.f)) * e3a;                                 \
    a2 = (a2 + a1) * es0v;                                                   \
    a1 = (a1 + a0 + (sk1 ? m1 : 0.f)) * e1a;                                 \
    a0 = (a0 + m1) * es0v;                                                   \
    m1 = (m1 + m2 + (skm1 ? m3 : 0.f)) * em1a;                               \
    /* sub-step 2 */                                                         \
    a8 = (a8 + a7) * es1v;                                                   \
    a7 = (a7 + a6 + (sk7 ? a5 : 0.f)) * e7b;                                 \
    a6 = (a6 + a5) * es1v;                                                   \
    a5 = (a5 + a4 + (sk5 ? a3 : 0.f)) * e5b;                                 \
    a4 = (a4 + a3) * es1v;                                                   \
    a3 = (a3 + a2 + (sk3 ? a1 : 0.f)) * e3b;                                 \
    a2 = (a2 + a1) * es1v;                                                   \
    a1 = (a1 + a0 + (sk1 ? m1 : 0.f)) * e1b;                                 \
    a0 = (a0 + m1) * es1v;                                                   \
    C0 = ROWL(P0); C1 = ROWL(P1);                 /* refill ring slots */    \
    if (DOREN) RENORM();                                                     \
    /* gathers for next pair FIRST (in-order DS: partial waits possible) */  \
    es0v = rdlane(N0, 57);                                                   \
    e1a = bperm(N0, ad1); e3a = bperm(N0, ad3);                              \
    e5a = bperm(N0, ad5); e7a = bperm(N0, ad7);                              \
    em1a = bperm(N0, adm1);                                                  \
    es1v = rdlane(N1, 57);                                                   \
    e1b = bperm(N1, ad1); e3b = bperm(N1, ad3);                              \
    e5b = bperm(N1, ad5); e7b = bperm(N1, ad7);                              \
    /* boundary shuffles (states 8k-3..8k-1 + frame) */                      \
    m3 = __shfl_up(a5, 1); m2 = __shfl_up(a6, 1); m1 = __shfl_up(a7, 1);     \
    eL = __shfl_up(eps, 1);                                                  \
    if (lane == 0) { m1 = 0.f; m2 = 0.f; m3 = 0.f; }                         \
  } while (0)

  int t0 = 1;
  for (; t0 + 8 <= len; t0 += 8) {
    int tmax = t0 + 15;
    if (tmax > len - 1) tmax = len - 1;
    WAITC(tmax >> 7);                            // gate ring refills t0+8..+15
    PAIR(rr0, rr1, rr2, rr3, t0 + 8,  t0 + 9,  false);
    PAIR(rr2, rr3, rr4, rr5, t0 + 10, t0 + 11, false);
    PAIR(rr4, rr5, rr6, rr7, t0 + 12, t0 + 13, false);
    PAIR(rr6, rr7, rr0, rr1, t0 + 14, t0 + 15, true);  // t0+7 == 0 mod 8
  }

  WAITC((len - 1) >> 7);                         // cover tail reads

  // tail: <= 7 single steps (m1/eL re-shuffled each step)
  for (int t = t0; t < len; ++t) {
    float cur = ROWL(t);
    float esv = rdlane(cur, 57);
    float e1v = bperm(cur, ad1), e3v = bperm(cur, ad3);
    float e5v = bperm(cur, ad5), e7v = bperm(cur, ad7);
    ksum += cur;
    if (!act) eps = eL;
    bool inc = (lane != 0) && (m1 != 0.f);
    int d = inc ? (eL - eps) : 0;
    float m1s;
    if (__builtin_expect(d > 24, 0)) {
      a0 = ldexpf(a0, -d); a1 = ldexpf(a1, -d); a2 = ldexpf(a2, -d);
      a3 = ldexpf(a3, -d); a4 = ldexpf(a4, -d); a5 = ldexpf(a5, -d);
      a6 = ldexpf(a6, -d); a7 = ldexpf(a7, -d); a8 = ldexpf(a8, -d);
      eps += d; m1s = m1;
    } else {
      m1s = inc ? ldexpf(m1, d) : 0.f;
    }
    act = act || (m1s != 0.f);
    a8 = (a8 + a7) * esv;
    a7 = (a7 + a6 + (sk7 ? a5 : 0.f)) * e7v;
    a6 = (a6 + a5) * esv;
    a5 = (a5 + a4 + (sk5 ? a3 : 0.f)) * e5v;
    a4 = (a4 + a3) * esv;
    a3 = (a3 + a2 + (sk3 ? a1 : 0.f)) * e3v;
    a2 = (a2 + a1) * esv;
    a1 = (a1 + a0 + (sk1 ? m1s : 0.f)) * e1v;
    a0 = (a0 + m1s) * esv;
    if ((t & 7) == 0) RENORM();
    m1 = __shfl_up(a7, 1);
    eL = __shfl_up(eps, 1);
    if (lane == 0) m1 = 0.f;
  }

  // final reduce — all cross-lane via shfl (no LDS / no barrier)
  int last = 2 * tl;
  int kx = last >> 3, jx = last & 7;
  if (kx > 63) { kx = 63; jx = last - 504; }     // state 512 -> lane63 a8
  int ky = (last - 1) >> 3, jy = (last - 1) & 7;
  float vx = pick9(jx, a0, a1, a2, a3, a4, a5, a6, a7, a8);
  float vy = pick9(jy, a0, a1, a2, a3, a4, a5, a6, a7, a8);
  float k56 = __shfl(ksum, 56);
  float sx = __shfl(vx, kx); int ex = __shfl(eps, kx);
  float sy = __shfl(vy, ky); int ey = __shfl(eps, ky);
  if (lane == 0) {
    int em = (ex > ey) ? ex : ey;
    float v = ldexpf(sx, ex - em) + ldexpf(sy, ey - em);
    float score = logf(v) + (float)em * LN2f - k56;
    partial[n] = -score / (float)tl;
  }
#undef WAITC
#undef ROWL
#undef RENORM
#undef PAIR
}

// ---------------------------------------------------------------------------
// Kernel 3: mean over batch
// ---------------------------------------------------------------------------
__global__ void reduce_mean(const float* __restrict__ partial,
                            float* __restrict__ out, int B) {
  float v = 0.f;
  for (int i = threadIdx.x; i < B; i += 64) v += partial[i];
  #pragma unroll
  for (int off = 32; off > 0; off >>= 1) v += __shfl_down(v, off, 64);
  if (threadIdx.x == 0) out[0] = v / (float)B;
}

extern "C" void kernel_launch(void* const* d_in, const int* in_sizes, int n_in,
                              void* d_out, int out_size, void* d_ws, size_t ws_size,
                              hipStream_t stream) {
  const float* feat = (const float*)d_in[0];
  const float* W = (const float*)d_in[1];
  const float* bias = (const float*)d_in[2];
  const int* targets = (const int*)d_in[3];
  const int* in_len = (const int*)d_in[4];
  const int* tgt_len = (const int*)d_in[5];
  float* out = (float*)d_out;

  const int V = in_sizes[2];
  const int D = in_sizes[1] / V;
  const int B = in_sizes[4];
  const int T = in_sizes[0] / (B * D);
  const int S = in_sizes[3] / B;
  const int nrows = B * T;

  float* pt = (float*)d_ws;                         // nrows*64 fp32
  float* partial = pt + (size_t)nrows * 64;         // B fp32
  short* Wb = (short*)(partial + B);                // 64*D bf16
  const int CPB = (T + 127) / 128;                  // time-chunks per batch
  int* flags = (int*)((char*)Wb + (size_t)64 * D * sizeof(short));  // B*CPB

  hipMemsetAsync(flags, 0, (size_t)B * CPB * sizeof(int), stream);

  conv_w<<<(64 * D + 255) / 256, 256, 0, stream>>>(W, Wb, V, D);

  // one fused dispatch: B consumer blocks first (resident from t=0),
  // then B*CPB producer blocks in t-major order.
  fused_gemm_star<<<dim3(B + B * CPB), 256, 0, stream>>>(
      feat, Wb, bias, pt, flags, targets, in_len, tgt_len, partial,
      nrows, D, V, T, S, B, CPB);

  reduce_mean<<<1, 64, 0, stream>>>(partial, out, B);
}

// Round 2
// 721.191 us; speedup vs baseline: 1.0466x; 1.0466x over previous
//
#include <hip/hip_runtime.h>
#include <hip/hip_bf16.h>
#include <math.h>

typedef __attribute__((ext_vector_type(4))) float f32x4;
typedef __attribute__((ext_vector_type(8))) short s16x8;

#define LOG2E 1.4426950408889634f
#define LN2f  0.6931471805599453f
#define INV_E 0.36787944117144233f

__device__ __forceinline__ short bfc(float x) {
  unsigned u = __float_as_uint(x);
  unsigned r = u + 0x7fffu + ((u >> 16) & 1u);   // RNE to bf16
  return (short)(r >> 16);
}

__device__ __forceinline__ unsigned pk2(float x, float y) {
  union { __hip_bfloat162 h; unsigned u; } c;
  c.h = __float22bfloat162_rn(make_float2(x, y));  // v_cvt_pk_bf16_f32
  return c.u;
}

__device__ __forceinline__ float rdlane(float v, int lane) {
  return __int_as_float(__builtin_amdgcn_readlane(__float_as_int(v), lane));
}

__device__ __forceinline__ float pick9(int j, float a0, float a1, float a2,
                                       float a3, float a4, float a5, float a6,
                                       float a7, float a8) {
  float v = a0;
  if (j == 1) v = a1;
  if (j == 2) v = a2;
  if (j == 3) v = a3;
  if (j == 4) v = a4;
  if (j == 5) v = a5;
  if (j == 6) v = a6;
  if (j == 7) v = a7;
  if (j == 8) v = a8;
  return v;
}

// ---------------------------------------------------------------------------
// Kernel 0: W (V x D fp32) -> Wb (64 x D bf16), rows >= V zero-filled.
// ---------------------------------------------------------------------------
__global__ void conv_w(const float* __restrict__ W, short* __restrict__ Wb,
                       int V, int D) {
  int idx = blockIdx.x * blockDim.x + threadIdx.x;
  if (idx >= 64 * D) return;
  int row = idx / D, col = idx - row * D;
  Wb[idx] = (row < V) ? bfc(W[(size_t)row * D + col]) : (short)0;
}

// ---------------------------------------------------------------------------
// Fused kernel v2:
//   blocks [0, B)    : star-CTC DP consumer (1 wave; waves 1-3 return).
//   blocks [B, B+P)  : PERSISTENT producers. Block p walks tiles
//                      i = p, p+P, ... in c-major order (tile i: c=i/B,
//                      b=i%B; 128 rows each) -> chunk wavefront so early
//                      chunks complete early (true pipeline).
// Producer also PRE-GATHERS emissions into DP layout:
//   ptg[row][lane] = float4(e1,e3,e5,e7) for DP lane's 4 token states
//   sk[row]        = float2(star~, ln s)
// so the DP inner loop has NO ds_bpermute (em1 = shfl_up of e7).
// Sync: per-(b,c) flag, RELEASE store; consumer polls with RELAXED
// agent-scope loads (coherent but no cache-invalidate) and issues ONE
// acquire fence per chunk crossing (the round-1 acquire-spin invalidated
// L2 every ~130 cycles and killed both phases).
// ---------------------------------------------------------------------------
__global__ __launch_bounds__(256) void fused_gemm_star(
    const float* __restrict__ feat, const short* __restrict__ Wb,
    const float* __restrict__ bias, float* __restrict__ ptg,
    float* __restrict__ skb, int* __restrict__ flags,
    const int* __restrict__ targets, const int* __restrict__ in_len,
    const int* __restrict__ tgt_len, float* __restrict__ partial,
    int nrows, int D, int V, int T, int S, int B, int CPB) {

  __shared__ float gbuf[4][4][64];   // [wave][row-in-iter][class]

  if ((int)blockIdx.x >= B) {
    // ======================= persistent producer ==========================
    const int NPROD = gridDim.x - B;
    const int NTILES = B * CPB;
    const int lane = threadIdx.x & 63;
    const int wave = threadIdx.x >> 6;
    const int m_lo = lane & 15;
    const int q = lane >> 4;
    const size_t bstr = (size_t)16 * D;

    for (int i = blockIdx.x - B; i < NTILES; i += NPROD) {
      const int c = i / B;
      const int b = i - c * B;
      const int tc0 = c * 128;
      const int rlen = (T - tc0 < 128) ? (T - tc0) : 128;
      const int rowlim = b * T + tc0 + rlen;
      const int rowbase = b * T + tc0 + wave * 32;

      // DP-lane labels for this batch (gather indices)
      const int* tg = targets + (size_t)b * S;
      const int l0 = lane * 4;
      const int g1 = (l0 < S) ? tg[l0] : 0;
      const int g3 = (l0 + 1 < S) ? tg[l0 + 1] : 0;
      const int g5 = (l0 + 2 < S) ? tg[l0 + 2] : 0;
      const int g7 = (l0 + 3 < S) ? tg[l0 + 3] : 0;

      int arow0 = rowbase + m_lo;
      int arow1 = rowbase + 16 + m_lo;
      if (arow0 >= nrows) arow0 = nrows - 1;     // clamp loads; stores guarded
      if (arow1 >= nrows) arow1 = nrows - 1;
      const short* Bp = Wb + (size_t)m_lo * D + q * 8;

      f32x4 acc[2][4];
      #pragma unroll
      for (int g = 0; g < 2; ++g)
        #pragma unroll
        for (int ni = 0; ni < 4; ++ni) acc[g][ni] = (f32x4){0.f, 0.f, 0.f, 0.f};

      const float* Ap0 = feat + (size_t)arow0 * D + q * 8;
      const float* Ap1 = feat + (size_t)arow1 * D + q * 8;
      float4 al0 = *(const float4*)(Ap0);
      float4 ah0 = *(const float4*)(Ap0 + 4);
      float4 al1 = *(const float4*)(Ap1);
      float4 ah1 = *(const float4*)(Ap1 + 4);
      s16x8 b0 = *(const s16x8*)(Bp);
      s16x8 b1 = *(const s16x8*)(Bp + bstr);
      s16x8 b2 = *(const s16x8*)(Bp + 2 * bstr);
      s16x8 b3 = *(const s16x8*)(Bp + 3 * bstr);

      for (int k0 = 0; k0 < D; k0 += 32) {
        const int kn = (k0 + 32 < D) ? (k0 + 32) : 0;  // dummy reload last iter
        const float* Ap0n = feat + (size_t)arow0 * D + kn + q * 8;
        const float* Ap1n = feat + (size_t)arow1 * D + kn + q * 8;
        const short* Bpn = Wb + (size_t)m_lo * D + kn + q * 8;
        float4 nal0 = *(const float4*)(Ap0n);
        float4 nah0 = *(const float4*)(Ap0n + 4);
        float4 nal1 = *(const float4*)(Ap1n);
        float4 nah1 = *(const float4*)(Ap1n + 4);
        s16x8 nb0 = *(const s16x8*)(Bpn);
        s16x8 nb1 = *(const s16x8*)(Bpn + bstr);
        s16x8 nb2 = *(const s16x8*)(Bpn + 2 * bstr);
        s16x8 nb3 = *(const s16x8*)(Bpn + 3 * bstr);

        union { s16x8 v; unsigned u[4]; } av0, av1;
        av0.u[0] = pk2(al0.x, al0.y); av0.u[1] = pk2(al0.z, al0.w);
        av0.u[2] = pk2(ah0.x, ah0.y); av0.u[3] = pk2(ah0.z, ah0.w);
        av1.u[0] = pk2(al1.x, al1.y); av1.u[1] = pk2(al1.z, al1.w);
        av1.u[2] = pk2(ah1.x, ah1.y); av1.u[3] = pk2(ah1.z, ah1.w);

        acc[0][0] = __builtin_amdgcn_mfma_f32_16x16x32_bf16(av0.v, b0, acc[0][0], 0, 0, 0);
        acc[0][1] = __builtin_amdgcn_mfma_f32_16x16x32_bf16(av0.v, b1, acc[0][1], 0, 0, 0);
        acc[0][2] = __builtin_amdgcn_mfma_f32_16x16x32_bf16(av0.v, b2, acc[0][2], 0, 0, 0);
        acc[0][3] = __builtin_amdgcn_mfma_f32_16x16x32_bf16(av0.v, b3, acc[0][3], 0, 0, 0);
        acc[1][0] = __builtin_amdgcn_mfma_f32_16x16x32_bf16(av1.v, b0, acc[1][0], 0, 0, 0);
        acc[1][1] = __builtin_amdgcn_mfma_f32_16x16x32_bf16(av1.v, b1, acc[1][1], 0, 0, 0);
        acc[1][2] = __builtin_amdgcn_mfma_f32_16x16x32_bf16(av1.v, b2, acc[1][2], 0, 0, 0);
        acc[1][3] = __builtin_amdgcn_mfma_f32_16x16x32_bf16(av1.v, b3, acc[1][3], 0, 0, 0);

        al0 = nal0; ah0 = nah0; al1 = nal1; ah1 = nah1;
        b0 = nb0; b1 = nb1; b2 = nb2; b3 = nb3;
      }

      float bias_v[4];
      #pragma unroll
      for (int ni = 0; ni < 4; ++ni) {
        int col = ni * 16 + m_lo;
        bias_v[ni] = (col < V) ? bias[col] : 0.f;
      }

      // C/D layout: col = lane&15, row = (lane>>4)*4 + reg   [m89-verified]
      #pragma unroll
      for (int g = 0; g < 2; ++g) {
        #pragma unroll
        for (int r = 0; r < 4; ++r) {
          float lg[4];
          #pragma unroll
          for (int ni = 0; ni < 4; ++ni) {
            int col = ni * 16 + m_lo;
            lg[ni] = (col < V) ? (acc[g][ni][r] + bias_v[ni]) : -1e30f;
          }
          float m = fmaxf(fmaxf(lg[0], lg[1]), fmaxf(lg[2], lg[3]));
          #pragma unroll
          for (int off = 1; off < 16; off <<= 1) m = fmaxf(m, __shfl_xor(m, off));
          float p[4];
          #pragma unroll
          for (int ni = 0; ni < 4; ++ni) p[ni] = exp2f((lg[ni] - m) * LOG2E);
          float s = (p[0] + p[1]) + (p[2] + p[3]);
          #pragma unroll
          for (int off = 1; off < 16; off <<= 1) s += __shfl_xor(s, off);

          // stage the 4 rows of this (g,r) iter into LDS, class-indexed
          #pragma unroll
          for (int ni = 0; ni < 4; ++ni)
            gbuf[wave][q][ni * 16 + m_lo] = p[ni];

          // gather + store DP-ready rows (wave-internal DS ordering)
          #pragma unroll
          for (int rr = 0; rr < 4; ++rr) {
            int grow = rowbase + g * 16 + rr * 4 + r;
            if (grow < rowlim) {
              float srow = rdlane(s, rr * 16);
              float4 ev;
              ev.x = gbuf[wave][rr][g1];
              ev.y = gbuf[wave][rr][g3];
              ev.z = gbuf[wave][rr][g5];
              ev.w = gbuf[wave][rr][g7];
              *(float4*)(ptg + ((size_t)grow * 64 + lane) * 4) = ev;
              if (lane == 0) {
                float2 skv;
                skv.x = srow * INV_E;      // star~ emission
                skv.y = logf(srow);       // K_t (ln units)
                *(float2*)(skb + (size_t)grow * 2) = skv;
              }
            }
          }
        }
      }

      __syncthreads();                 // all 4 waves' stores issued+drained
      if (threadIdx.x == 0)
        __hip_atomic_store(&flags[b * CPB + c], 1, __ATOMIC_RELEASE,
                           __HIP_MEMORY_SCOPE_AGENT);
    }
    return;
  }

  // ================= consumer: star-CTC DP (1 wave / sequence) =============
  if (threadIdx.x >= 64) return;
  const int n = blockIdx.x;
  const int lane = threadIdx.x;
  const int len = in_len[n];
  const int tl = tgt_len[n];
  const int* tg = targets + (size_t)n * S;
  const int* fl = flags + n * CPB;
  const float* prow = ptg + (size_t)n * T * 256;
  const float* srow = skb + (size_t)n * T * 2;

  int cdone = -1;
#define WAITC(cc)                                                            \
  do {                                                                       \
    int _c = (cc);                                                           \
    if (cdone < _c) {                                                        \
      while (cdone < _c) {                                                   \
        if (__hip_atomic_load((int*)&fl[cdone + 1], __ATOMIC_RELAXED,        \
                              __HIP_MEMORY_SCOPE_AGENT))                     \
          ++cdone;                                                           \
        else                                                                 \
          __builtin_amdgcn_s_sleep(8);                                       \
      }                                                                      \
      __builtin_amdgcn_fence(__ATOMIC_ACQUIRE, "agent");                     \
    }                                                                        \
  } while (0)

  const int s0 = lane * 4;
  int lab1 = (s0     < S) ? tg[s0]     : 0;
  int lab3 = (s0 + 1 < S) ? tg[s0 + 1] : 0;
  int lab5 = (s0 + 2 < S) ? tg[s0 + 2] : 0;
  int lab7 = (s0 + 3 < S) ? tg[s0 + 3] : 0;
  int labm1 = __shfl_up(lab7, 1);                // label of state 8k-1
  int labm3 = __shfl_up(lab5, 1);                // label of state 8k-3
  const bool sk1 = (lane > 0) && (lab1 != labm1);
  const bool sk3 = (lab3 != lab1);
  const bool sk5 = (lab5 != lab3);
  const bool sk7 = (lab7 != lab5);
  const bool skm1 = (labm1 != labm3);

  float a0 = 0, a1 = 0, a2 = 0, a3 = 0, a4 = 0, a5 = 0, a6 = 0, a7 = 0, a8 = 0;
  float m1 = 0.f, m2 = 0.f, m3 = 0.f;
  int eps = 0, eL = 0;
  bool act = (lane == 0);

#define PTGL(t) (*(const float4*)(prow +                                     \
    ((size_t)(((t) < len) ? (t) : (len - 1)) * 256 + lane * 4)))
#define SKLL(t) (*(const float2*)(srow +                                     \
    ((size_t)(((t) < len) ? (t) : (len - 1)) * 2)))

  WAITC(0);                                      // rows 0..8 live in chunk 0

  // t = 0
  float4 r0 = PTGL(0);
  float2 k0v = SKLL(0);
  if (lane == 0) { a0 = k0v.x; a1 = r0.x; }      // star~, e1 = p[tg[0]]
  float ksum = k0v.y;                            // uniform across lanes

  // prefetch ring: rows 1..8 (emissions + star/K)
  float4 rr0 = PTGL(1), rr1 = PTGL(2), rr2 = PTGL(3), rr3 = PTGL(4);
  float4 rr4 = PTGL(5), rr5 = PTGL(6), rr6 = PTGL(7), rr7 = PTGL(8);
  float2 kr0 = SKLL(1), kr1 = SKLL(2), kr2 = SKLL(3), kr3 = SKLL(4);
  float2 kr4 = SKLL(5), kr5 = SKLL(6), kr6 = SKLL(7), kr7 = SKLL(8);

  float em1a = __shfl_up(rr0.w, 1);              // e_{8k-1} for first pair

#define RENORM()                                                             \
  do {                                                                       \
    float mx = fmaxf(fmaxf(fmaxf(a0, a1), fmaxf(a2, a3)),                    \
                     fmaxf(fmaxf(a4, a5), fmaxf(a6, a7)));                   \
    mx = fmaxf(mx, a8);                                                      \
    int e = (int)((__float_as_uint(mx) >> 23) & 255) - 126;                  \
    e = (act && mx > 0.f) ? e : 0;                                           \
    a0 = ldexpf(a0, -e); a1 = ldexpf(a1, -e); a2 = ldexpf(a2, -e);           \
    a3 = ldexpf(a3, -e); a4 = ldexpf(a4, -e); a5 = ldexpf(a5, -e);           \
    a6 = ldexpf(a6, -e); a7 = ldexpf(a7, -e); a8 = ldexpf(a8, -e);           \
    eps += e;                                                                \
  } while (0)

#define PAIR(EC0, EC1, KC0, KC1, NX, P0, P1, DOREN)                          \
  do {                                                                       \
    ksum += KC0.y; ksum += KC1.y;                                            \
    if (!act) eps = eL;                                                      \
    bool inc = (lane != 0) &&                                                \
               ((m1 != 0.f) || (m2 != 0.f) || (m3 != 0.f));                  \
    int d = inc ? (eL - eps) : 0;                                            \
    if (__builtin_expect(d > 24, 0)) {            /* raise own frame */      \
      a0 = ldexpf(a0, -d); a1 = ldexpf(a1, -d); a2 = ldexpf(a2, -d);         \
      a3 = ldexpf(a3, -d); a4 = ldexpf(a4, -d); a5 = ldexpf(a5, -d);         \
      a6 = ldexpf(a6, -d); a7 = ldexpf(a7, -d); a8 = ldexpf(a8, -d);         \
      eps += d;                                   /* m stay in frame eL */   \
    } else {                                                                 \
      m1 = ldexpf(m1, d); m2 = ldexpf(m2, d); m3 = ldexpf(m3, d);            \
    }                                                                        \
    act = act || (m1 != 0.f) || (m2 != 0.f) || (m3 != 0.f);                  \
    /* sub-step 1 (in-place top-down; uses old lower states) */              \
    a8 = (a8 + a7) * KC0.x;                                                  \
    a7 = (a7 + a6 + (sk7 ? a5 : 0.f)) * EC0.w;                               \
    a6 = (a6 + a5) * KC0.x;                                                  \
    a5 = (a5 + a4 + (sk5 ? a3 : 0.f)) * EC0.z;                               \
    a4 = (a4 + a3) * KC0.x;                                                  \
    a3 = (a3 + a2 + (sk3 ? a1 : 0.f)) * EC0.y;                               \
    a2 = (a2 + a1) * KC0.x;                                                  \
    a1 = (a1 + a0 + (sk1 ? m1 : 0.f)) * EC0.x;                               \
    a0 = (a0 + m1) * KC0.x;                                                  \
    m1 = (m1 + m2 + (skm1 ? m3 : 0.f)) * em1a;                               \
    /* sub-step 2 */                                                         \
    a8 = (a8 + a7) * KC1.x;                                                  \
    a7 = (a7 + a6 + (sk7 ? a5 : 0.f)) * EC1.w;                               \
    a6 = (a6 + a5) * KC1.x;                                                  \
    a5 = (a5 + a4 + (sk5 ? a3 : 0.f)) * EC1.z;                               \
    a4 = (a4 + a3) * KC1.x;                                                  \
    a3 = (a3 + a2 + (sk3 ? a1 : 0.f)) * EC1.y;                               \
    a2 = (a2 + a1) * KC1.x;                                                  \
    a1 = (a1 + a0 + (sk1 ? m1 : 0.f)) * EC1.x;                               \
    a0 = (a0 + m1) * KC1.x;                                                  \
    EC0 = PTGL(P0); EC1 = PTGL(P1);               /* refill ring slots */    \
    KC0 = SKLL(P0); KC1 = SKLL(P1);                                          \
    if (DOREN) RENORM();                                                     \
    em1a = __shfl_up(NX.w, 1);                    /* next pair's e_{8k-1} */ \
    /* boundary shuffles (states 8k-3..8k-1 + frame) */                      \
    m3 = __shfl_up(a5, 1); m2 = __shfl_up(a6, 1); m1 = __shfl_up(a7, 1);     \
    eL = __shfl_up(eps, 1);                                                  \
    if (lane == 0) { m1 = 0.f; m2 = 0.f; m3 = 0.f; }                         \
  } while (0)

  int t0 = 1;
  for (; t0 + 8 <= len; t0 += 8) {
    int tmax = t0 + 15;
    if (tmax > len - 1) tmax = len - 1;
    WAITC(tmax >> 7);                            // gate ring refills t0+8..+15
    PAIR(rr0, rr1, kr0, kr1, rr2, t0 + 8,  t0 + 9,  false);
    PAIR(rr2, rr3, kr2, kr3, rr4, t0 + 10, t0 + 11, false);
    PAIR(rr4, rr5, kr4, kr5, rr6, t0 + 12, t0 + 13, false);
    PAIR(rr6, rr7, kr6, kr7, rr0, t0 + 14, t0 + 15, true);  // t0+7==0 mod 8
  }

  WAITC((len - 1) >> 7);                         // cover tail reads

  // tail: <= 7 single steps (m1/eL re-shuffled each step; no em1 needed)
  for (int t = t0; t < len; ++t) {
    float4 cv = PTGL(t);
    float2 kc = SKLL(t);
    ksum += kc.y;
    if (!act) eps = eL;
    bool inc = (lane != 0) && (m1 != 0.f);
    int d = inc ? (eL - eps) : 0;
    float m1s;
    if (__builtin_expect(d > 24, 0)) {
      a0 = ldexpf(a0, -d); a1 = ldexpf(a1, -d); a2 = ldexpf(a2, -d);
      a3 = ldexpf(a3, -d); a4 = ldexpf(a4, -d); a5 = ldexpf(a5, -d);
      a6 = ldexpf(a6, -d); a7 = ldexpf(a7, -d); a8 = ldexpf(a8, -d);
      eps += d; m1s = m1;
    } else {
      m1s = inc ? ldexpf(m1, d) : 0.f;
    }
    act = act || (m1s != 0.f);
    a8 = (a8 + a7) * kc.x;
    a7 = (a7 + a6 + (sk7 ? a5 : 0.f)) * cv.w;
    a6 = (a6 + a5) * kc.x;
    a5 = (a5 + a4 + (sk5 ? a3 : 0.f)) * cv.z;
    a4 = (a4 + a3) * kc.x;
    a3 = (a3 + a2 + (sk3 ? a1 : 0.f)) * cv.y;
    a2 = (a2 + a1) * kc.x;
    a1 = (a1 + a0 + (sk1 ? m1s : 0.f)) * cv.x;
    a0 = (a0 + m1s) * kc.x;
    if ((t & 7) == 0) RENORM();
    m1 = __shfl_up(a7, 1);
    eL = __shfl_up(eps, 1);
    if (lane == 0) m1 = 0.f;
  }

  // final reduce — all cross-lane via shfl (no LDS / no barrier)
  int last = 2 * tl;
  int kx = last >> 3, jx = last & 7;
  if (kx > 63) { kx = 63; jx = last - 504; }     // state 512 -> lane63 a8
  int ky = (last - 1) >> 3, jy = (last - 1) & 7;
  float vx = pick9(jx, a0, a1, a2, a3, a4, a5, a6, a7, a8);
  float vy = pick9(jy, a0, a1, a2, a3, a4, a5, a6, a7, a8);
  float sx = __shfl(vx, kx); int ex = __shfl(eps, kx);
  float sy = __shfl(vy, ky); int ey = __shfl(eps, ky);
  if (lane == 0) {
    int em = (ex > ey) ? ex : ey;
    float v = ldexpf(sx, ex - em) + ldexpf(sy, ey - em);
    float score = logf(v) + (float)em * LN2f - ksum;
    partial[n] = -score / (float)tl;
  }
#undef WAITC
#undef PTGL
#undef SKLL
#undef RENORM
#undef PAIR
}

// ---------------------------------------------------------------------------
// Kernel 3: mean over batch
// ---------------------------------------------------------------------------
__global__ void reduce_mean(const float* __restrict__ partial,
                            float* __restrict__ out, int B) {
  float v = 0.f;
  for (int i = threadIdx.x; i < B; i += 64) v += partial[i];
  #pragma unroll
  for (int off = 32; off > 0; off >>= 1) v += __shfl_down(v, off, 64);
  if (threadIdx.x == 0) out[0] = v / (float)B;
}

extern "C" void kernel_launch(void* const* d_in, const int* in_sizes, int n_in,
                              void* d_out, int out_size, void* d_ws, size_t ws_size,
                              hipStream_t stream) {
  const float* feat = (const float*)d_in[0];
  const float* W = (const float*)d_in[1];
  const float* bias = (const float*)d_in[2];
  const int* targets = (const int*)d_in[3];
  const int* in_len = (const int*)d_in[4];
  const int* tgt_len = (const int*)d_in[5];
  float* out = (float*)d_out;

  const int V = in_sizes[2];
  const int D = in_sizes[1] / V;
  const int B = in_sizes[4];
  const int T = in_sizes[0] / (B * D);
  const int S = in_sizes[3] / B;
  const int nrows = B * T;

  float* ptg = (float*)d_ws;                        // nrows*256 fp32 (64 MB)
  float* skb = ptg + (size_t)nrows * 256;           // nrows*2 fp32
  float* partial = skb + (size_t)nrows * 2;         // B fp32
  short* Wb = (short*)(partial + B);                // 64*D bf16
  const int CPB = (T + 127) / 128;                  // time-chunks per batch
  int* flags = (int*)((char*)Wb + (size_t)64 * D * sizeof(short));  // B*CPB

  hipMemsetAsync(flags, 0, (size_t)B * CPB * sizeof(int), stream);

  conv_w<<<(64 * D + 255) / 256, 256, 0, stream>>>(W, Wb, V, D);

  // grid = exactly 256 blocks: B consumers (resident first) + 224
  // persistent producers (1 block/CU; 3-phase c-major chunk wavefront).
  int NPROD = 256 - B;
  const int NTILES = B * CPB;
  if (NPROD > NTILES) NPROD = NTILES;
  fused_gemm_star<<<dim3(B + NPROD), 256, 0, stream>>>(
      feat, Wb, bias, ptg, skb, flags, targets, in_len, tgt_len, partial,
      nrows, D, V, T, S, B, CPB);

  reduce_mean<<<1, 64, 0, stream>>>(partial, out, B);
}

// Round 3
// 715.124 us; speedup vs baseline: 1.0555x; 1.0085x over previous
//
#include <hip/hip_runtime.h>
#include <hip/hip_bf16.h>
#include <math.h>

typedef __attribute__((ext_vector_type(4))) float f32x4;
typedef __attribute__((ext_vector_type(8))) short s16x8;

#define LOG2E 1.4426950408889634f
#define LN2f  0.6931471805599453f
#define INV_E 0.36787944117144233f

__device__ __forceinline__ short bfc(float x) {
  unsigned u = __float_as_uint(x);
  unsigned r = u + 0x7fffu + ((u >> 16) & 1u);   // RNE to bf16
  return (short)(r >> 16);
}

__device__ __forceinline__ unsigned pk2(float x, float y) {
  union { __hip_bfloat162 h; unsigned u; } c;
  c.h = __float22bfloat162_rn(make_float2(x, y));  // v_cvt_pk_bf16_f32
  return c.u;
}

__device__ __forceinline__ float rdlane(float v, int lane) {
  return __int_as_float(__builtin_amdgcn_readlane(__float_as_int(v), lane));
}

__device__ __forceinline__ float pick9(int j, float a0, float a1, float a2,
                                       float a3, float a4, float a5, float a6,
                                       float a7, float a8) {
  float v = a0;
  if (j == 1) v = a1;
  if (j == 2) v = a2;
  if (j == 3) v = a3;
  if (j == 4) v = a4;
  if (j == 5) v = a5;
  if (j == 6) v = a6;
  if (j == 7) v = a7;
  if (j == 8) v = a8;
  return v;
}

// ---------------------------------------------------------------------------
// Kernel 0: W (V x D fp32) -> Wb (64 x D bf16), rows >= V zero-filled.
// ---------------------------------------------------------------------------
__global__ void conv_w(const float* __restrict__ W, short* __restrict__ Wb,
                       int V, int D) {
  int idx = blockIdx.x * blockDim.x + threadIdx.x;
  if (idx >= 64 * D) return;
  int row = idx / D, col = idx - row * D;
  Wb[idx] = (row < V) ? bfc(W[(size_t)row * D + col]) : (short)0;
}

// ---------------------------------------------------------------------------
// Fused kernel v3: identical structure to v2, but __launch_bounds__(256, 1).
// v2's VGPR_Count=60/76 proves hipcc targeted 8 waves/SIMD and register-
// starved BOTH the GEMM k-loop prefetch (needs >=112 live VGPRs) and the DP
// prefetch ring (48 VGPRs) -> every load serialized at HBM latency
// (~150us/tile, concurrency-independent). (256,1) = 1 wave/EU min -> up to
// 512 VGPRs; grid is exactly 256 blocks = 1 block/CU either way.
//   blocks [0, B)    : star-CTC DP consumer (1 wave; waves 1-3 return).
//   blocks [B, B+P)  : persistent producers, c-major tile walk (chunk
//                      wavefront: chunks 0-6 after round 0, 7-13 after
//                      round 1, 14-15 after round 2).
// Producer pre-gathers emissions into DP layout:
//   ptg[row][lane] = float4(e1,e3,e5,e7) for DP lane's 4 token states
//   sk[row]        = float2(star~, ln s)
// Sync: per-(b,c) flag, RELEASE store; consumer polls RELAXED agent-scope
// + one acquire fence per chunk crossing.
// ---------------------------------------------------------------------------
__global__ __launch_bounds__(256, 1) void fused_gemm_star(
    const float* __restrict__ feat, const short* __restrict__ Wb,
    const float* __restrict__ bias, float* __restrict__ ptg,
    float* __restrict__ skb, int* __restrict__ flags,
    const int* __restrict__ targets, const int* __restrict__ in_len,
    const int* __restrict__ tgt_len, float* __restrict__ partial,
    int nrows, int D, int V, int T, int S, int B, int CPB) {

  __shared__ float gbuf[4][4][64];   // [wave][row-in-iter][class]

  if ((int)blockIdx.x >= B) {
    // ======================= persistent producer ==========================
    const int NPROD = gridDim.x - B;
    const int NTILES = B * CPB;
    const int lane = threadIdx.x & 63;
    const int wave = threadIdx.x >> 6;
    const int m_lo = lane & 15;
    const int q = lane >> 4;
    const size_t bstr = (size_t)16 * D;

    for (int i = blockIdx.x - B; i < NTILES; i += NPROD) {
      const int c = i / B;
      const int b = i - c * B;
      const int tc0 = c * 128;
      const int rlen = (T - tc0 < 128) ? (T - tc0) : 128;
      const int rowlim = b * T + tc0 + rlen;
      const int rowbase = b * T + tc0 + wave * 32;

      // DP-lane labels for this batch (gather indices)
      const int* tg = targets + (size_t)b * S;
      const int l0 = lane * 4;
      const int g1 = (l0 < S) ? tg[l0] : 0;
      const int g3 = (l0 + 1 < S) ? tg[l0 + 1] : 0;
      const int g5 = (l0 + 2 < S) ? tg[l0 + 2] : 0;
      const int g7 = (l0 + 3 < S) ? tg[l0 + 3] : 0;

      int arow0 = rowbase + m_lo;
      int arow1 = rowbase + 16 + m_lo;
      if (arow0 >= nrows) arow0 = nrows - 1;     // clamp loads; stores guarded
      if (arow1 >= nrows) arow1 = nrows - 1;
      const short* Bp = Wb + (size_t)m_lo * D + q * 8;

      f32x4 acc[2][4];
      #pragma unroll
      for (int g = 0; g < 2; ++g)
        #pragma unroll
        for (int ni = 0; ni < 4; ++ni) acc[g][ni] = (f32x4){0.f, 0.f, 0.f, 0.f};

      const float* Ap0 = feat + (size_t)arow0 * D + q * 8;
      const float* Ap1 = feat + (size_t)arow1 * D + q * 8;
      float4 al0 = *(const float4*)(Ap0);
      float4 ah0 = *(const float4*)(Ap0 + 4);
      float4 al1 = *(const float4*)(Ap1);
      float4 ah1 = *(const float4*)(Ap1 + 4);
      s16x8 b0 = *(const s16x8*)(Bp);
      s16x8 b1 = *(const s16x8*)(Bp + bstr);
      s16x8 b2 = *(const s16x8*)(Bp + 2 * bstr);
      s16x8 b3 = *(const s16x8*)(Bp + 3 * bstr);

      for (int k0 = 0; k0 < D; k0 += 32) {
        const int kn = (k0 + 32 < D) ? (k0 + 32) : 0;  // dummy reload last iter
        const float* Ap0n = feat + (size_t)arow0 * D + kn + q * 8;
        const float* Ap1n = feat + (size_t)arow1 * D + kn + q * 8;
        const short* Bpn = Wb + (size_t)m_lo * D + kn + q * 8;
        float4 nal0 = *(const float4*)(Ap0n);
        float4 nah0 = *(const float4*)(Ap0n + 4);
        float4 nal1 = *(const float4*)(Ap1n);
        float4 nah1 = *(const float4*)(Ap1n + 4);
        s16x8 nb0 = *(const s16x8*)(Bpn);
        s16x8 nb1 = *(const s16x8*)(Bpn + bstr);
        s16x8 nb2 = *(const s16x8*)(Bpn + 2 * bstr);
        s16x8 nb3 = *(const s16x8*)(Bpn + 3 * bstr);

        union { s16x8 v; unsigned u[4]; } av0, av1;
        av0.u[0] = pk2(al0.x, al0.y); av0.u[1] = pk2(al0.z, al0.w);
        av0.u[2] = pk2(ah0.x, ah0.y); av0.u[3] = pk2(ah0.z, ah0.w);
        av1.u[0] = pk2(al1.x, al1.y); av1.u[1] = pk2(al1.z, al1.w);
        av1.u[2] = pk2(ah1.x, ah1.y); av1.u[3] = pk2(ah1.z, ah1.w);

        acc[0][0] = __builtin_amdgcn_mfma_f32_16x16x32_bf16(av0.v, b0, acc[0][0], 0, 0, 0);
        acc[0][1] = __builtin_amdgcn_mfma_f32_16x16x32_bf16(av0.v, b1, acc[0][1], 0, 0, 0);
        acc[0][2] = __builtin_amdgcn_mfma_f32_16x16x32_bf16(av0.v, b2, acc[0][2], 0, 0, 0);
        acc[0][3] = __builtin_amdgcn_mfma_f32_16x16x32_bf16(av0.v, b3, acc[0][3], 0, 0, 0);
        acc[1][0] = __builtin_amdgcn_mfma_f32_16x16x32_bf16(av1.v, b0, acc[1][0], 0, 0, 0);
        acc[1][1] = __builtin_amdgcn_mfma_f32_16x16x32_bf16(av1.v, b1, acc[1][1], 0, 0, 0);
        acc[1][2] = __builtin_amdgcn_mfma_f32_16x16x32_bf16(av1.v, b2, acc[1][2], 0, 0, 0);
        acc[1][3] = __builtin_amdgcn_mfma_f32_16x16x32_bf16(av1.v, b3, acc[1][3], 0, 0, 0);

        al0 = nal0; ah0 = nah0; al1 = nal1; ah1 = nah1;
        b0 = nb0; b1 = nb1; b2 = nb2; b3 = nb3;
      }

      float bias_v[4];
      #pragma unroll
      for (int ni = 0; ni < 4; ++ni) {
        int col = ni * 16 + m_lo;
        bias_v[ni] = (col < V) ? bias[col] : 0.f;
      }

      // C/D layout: col = lane&15, row = (lane>>4)*4 + reg   [m89-verified]
      #pragma unroll
      for (int g = 0; g < 2; ++g) {
        #pragma unroll
        for (int r = 0; r < 4; ++r) {
          float lg[4];
          #pragma unroll
          for (int ni = 0; ni < 4; ++ni) {
            int col = ni * 16 + m_lo;
            lg[ni] = (col < V) ? (acc[g][ni][r] + bias_v[ni]) : -1e30f;
          }
          float m = fmaxf(fmaxf(lg[0], lg[1]), fmaxf(lg[2], lg[3]));
          #pragma unroll
          for (int off = 1; off < 16; off <<= 1) m = fmaxf(m, __shfl_xor(m, off));
          float p[4];
          #pragma unroll
          for (int ni = 0; ni < 4; ++ni) p[ni] = exp2f((lg[ni] - m) * LOG2E);
          float s = (p[0] + p[1]) + (p[2] + p[3]);
          #pragma unroll
          for (int off = 1; off < 16; off <<= 1) s += __shfl_xor(s, off);

          // stage the 4 rows of this (g,r) iter into LDS, class-indexed
          #pragma unroll
          for (int ni = 0; ni < 4; ++ni)
            gbuf[wave][q][ni * 16 + m_lo] = p[ni];

          // gather + store DP-ready rows (wave-internal DS ordering)
          #pragma unroll
          for (int rr = 0; rr < 4; ++rr) {
            int grow = rowbase + g * 16 + rr * 4 + r;
            if (grow < rowlim) {
              float srow = rdlane(s, rr * 16);
              float4 ev;
              ev.x = gbuf[wave][rr][g1];
              ev.y = gbuf[wave][rr][g3];
              ev.z = gbuf[wave][rr][g5];
              ev.w = gbuf[wave][rr][g7];
              *(float4*)(ptg + ((size_t)grow * 64 + lane) * 4) = ev;
              if (lane == 0) {
                float2 skv;
                skv.x = srow * INV_E;      // star~ emission
                skv.y = logf(srow);       // K_t (ln units)
                *(float2*)(skb + (size_t)grow * 2) = skv;
              }
            }
          }
        }
      }

      __syncthreads();                 // all 4 waves' stores issued+drained
      if (threadIdx.x == 0)
        __hip_atomic_store(&flags[b * CPB + c], 1, __ATOMIC_RELEASE,
                           __HIP_MEMORY_SCOPE_AGENT);
    }
    return;
  }

  // ================= consumer: star-CTC DP (1 wave / sequence) =============
  if (threadIdx.x >= 64) return;
  const int n = blockIdx.x;
  const int lane = threadIdx.x;
  const int len = in_len[n];
  const int tl = tgt_len[n];
  const int* tg = targets + (size_t)n * S;
  const int* fl = flags + n * CPB;
  const float* prow = ptg + (size_t)n * T * 256;
  const float* srow = skb + (size_t)n * T * 2;

  int cdone = -1;
#define WAITC(cc)                                                            \
  do {                                                                       \
    int _c = (cc);                                                           \
    if (cdone < _c) {                                                        \
      while (cdone < _c) {                                                   \
        if (__hip_atomic_load((int*)&fl[cdone + 1], __ATOMIC_RELAXED,        \
                              __HIP_MEMORY_SCOPE_AGENT))                     \
          ++cdone;                                                           \
        else                                                                 \
          __builtin_amdgcn_s_sleep(8);                                       \
      }                                                                      \
      __builtin_amdgcn_fence(__ATOMIC_ACQUIRE, "agent");                     \
    }                                                                        \
  } while (0)

  const int s0 = lane * 4;
  int lab1 = (s0     < S) ? tg[s0]     : 0;
  int lab3 = (s0 + 1 < S) ? tg[s0 + 1] : 0;
  int lab5 = (s0 + 2 < S) ? tg[s0 + 2] : 0;
  int lab7 = (s0 + 3 < S) ? tg[s0 + 3] : 0;
  int labm1 = __shfl_up(lab7, 1);                // label of state 8k-1
  int labm3 = __shfl_up(lab5, 1);                // label of state 8k-3
  const bool sk1 = (lane > 0) && (lab1 != labm1);
  const bool sk3 = (lab3 != lab1);
  const bool sk5 = (lab5 != lab3);
  const bool sk7 = (lab7 != lab5);
  const bool skm1 = (labm1 != labm3);

  float a0 = 0, a1 = 0, a2 = 0, a3 = 0, a4 = 0, a5 = 0, a6 = 0, a7 = 0, a8 = 0;
  float m1 = 0.f, m2 = 0.f, m3 = 0.f;
  int eps = 0, eL = 0;
  bool act = (lane == 0);

#define PTGL(t) (*(const float4*)(prow +                                     \
    ((size_t)(((t) < len) ? (t) : (len - 1)) * 256 + lane * 4)))
#define SKLL(t) (*(const float2*)(srow +                                     \
    ((size_t)(((t) < len) ? (t) : (len - 1)) * 2)))

  WAITC(0);                                      // rows 0..8 live in chunk 0

  // t = 0
  float4 r0 = PTGL(0);
  float2 k0v = SKLL(0);
  if (lane == 0) { a0 = k0v.x; a1 = r0.x; }      // star~, e1 = p[tg[0]]
  float ksum = k0v.y;                            // uniform across lanes

  // prefetch ring: rows 1..8 (emissions + star/K)
  float4 rr0 = PTGL(1), rr1 = PTGL(2), rr2 = PTGL(3), rr3 = PTGL(4);
  float4 rr4 = PTGL(5), rr5 = PTGL(6), rr6 = PTGL(7), rr7 = PTGL(8);
  float2 kr0 = SKLL(1), kr1 = SKLL(2), kr2 = SKLL(3), kr3 = SKLL(4);
  float2 kr4 = SKLL(5), kr5 = SKLL(6), kr6 = SKLL(7), kr7 = SKLL(8);

  float em1a = __shfl_up(rr0.w, 1);              // e_{8k-1} for first pair

#define RENORM()                                                             \
  do {                                                                       \
    float mx = fmaxf(fmaxf(fmaxf(a0, a1), fmaxf(a2, a3)),                    \
                     fmaxf(fmaxf(a4, a5), fmaxf(a6, a7)));                   \
    mx = fmaxf(mx, a8);                                                      \
    int e = (int)((__float_as_uint(mx) >> 23) & 255) - 126;                  \
    e = (act && mx > 0.f) ? e : 0;                                           \
    a0 = ldexpf(a0, -e); a1 = ldexpf(a1, -e); a2 = ldexpf(a2, -e);           \
    a3 = ldexpf(a3, -e); a4 = ldexpf(a4, -e); a5 = ldexpf(a5, -e);           \
    a6 = ldexpf(a6, -e); a7 = ldexpf(a7, -e); a8 = ldexpf(a8, -e);           \
    eps += e;                                                                \
  } while (0)

#define PAIR(EC0, EC1, KC0, KC1, NX, P0, P1, DOREN)                          \
  do {                                                                       \
    ksum += KC0.y; ksum += KC1.y;                                            \
    if (!act) eps = eL;                                                      \
    bool inc = (lane != 0) &&                                                \
               ((m1 != 0.f) || (m2 != 0.f) || (m3 != 0.f));                  \
    int d = inc ? (eL - eps) : 0;                                            \
    if (__builtin_expect(d > 24, 0)) {            /* raise own frame */      \
      a0 = ldexpf(a0, -d); a1 = ldexpf(a1, -d); a2 = ldexpf(a2, -d);         \
      a3 = ldexpf(a3, -d); a4 = ldexpf(a4, -d); a5 = ldexpf(a5, -d);         \
      a6 = ldexpf(a6, -d); a7 = ldexpf(a7, -d); a8 = ldexpf(a8, -d);         \
      eps += d;                                   /* m stay in frame eL */   \
    } else {                                                                 \
      m1 = ldexpf(m1, d); m2 = ldexpf(m2, d); m3 = ldexpf(m3, d);            \
    }                                                                        \
    act = act || (m1 != 0.f) || (m2 != 0.f) || (m3 != 0.f);                  \
    /* sub-step 1 (in-place top-down; uses old lower states) */              \
    a8 = (a8 + a7) * KC0.x;                                                  \
    a7 = (a7 + a6 + (sk7 ? a5 : 0.f)) * EC0.w;                               \
    a6 = (a6 + a5) * KC0.x;                                                  \
    a5 = (a5 + a4 + (sk5 ? a3 : 0.f)) * EC0.z;                               \
    a4 = (a4 + a3) * KC0.x;                                                  \
    a3 = (a3 + a2 + (sk3 ? a1 : 0.f)) * EC0.y;                               \
    a2 = (a2 + a1) * KC0.x;                                                  \
    a1 = (a1 + a0 + (sk1 ? m1 : 0.f)) * EC0.x;                               \
    a0 = (a0 + m1) * KC0.x;                                                  \
    m1 = (m1 + m2 + (skm1 ? m3 : 0.f)) * em1a;                               \
    /* sub-step 2 */                                                         \
    a8 = (a8 + a7) * KC1.x;                                                  \
    a7 = (a7 + a6 + (sk7 ? a5 : 0.f)) * EC1.w;                               \
    a6 = (a6 + a5) * KC1.x;                                                  \
    a5 = (a5 + a4 + (sk5 ? a3 : 0.f)) * EC1.z;                               \
    a4 = (a4 + a3) * KC1.x;                                                  \
    a3 = (a3 + a2 + (sk3 ? a1 : 0.f)) * EC1.y;                               \
    a2 = (a2 + a1) * KC1.x;                                                  \
    a1 = (a1 + a0 + (sk1 ? m1 : 0.f)) * EC1.x;                               \
    a0 = (a0 + m1) * KC1.x;                                                  \
    EC0 = PTGL(P0); EC1 = PTGL(P1);               /* refill ring slots */    \
    KC0 = SKLL(P0); KC1 = SKLL(P1);                                          \
    if (DOREN) RENORM();                                                     \
    em1a = __shfl_up(NX.w, 1);                    /* next pair's e_{8k-1} */ \
    /* boundary shuffles (states 8k-3..8k-1 + frame) */                      \
    m3 = __shfl_up(a5, 1); m2 = __shfl_up(a6, 1); m1 = __shfl_up(a7, 1);     \
    eL = __shfl_up(eps, 1);                                                  \
    if (lane == 0) { m1 = 0.f; m2 = 0.f; m3 = 0.f; }                         \
  } while (0)

  int t0 = 1;
  for (; t0 + 8 <= len; t0 += 8) {
    int tmax = t0 + 15;
    if (tmax > len - 1) tmax = len - 1;
    WAITC(tmax >> 7);                            // gate ring refills t0+8..+15
    PAIR(rr0, rr1, kr0, kr1, rr2, t0 + 8,  t0 + 9,  false);
    PAIR(rr2, rr3, kr2, kr3, rr4, t0 + 10, t0 + 11, false);
    PAIR(rr4, rr5, kr4, kr5, rr6, t0 + 12, t0 + 13, false);
    PAIR(rr6, rr7, kr6, kr7, rr0, t0 + 14, t0 + 15, true);  // t0+7==0 mod 8
  }

  WAITC((len - 1) >> 7);                         // cover tail reads

  // tail: <= 7 single steps (m1/eL re-shuffled each step; no em1 needed)
  for (int t = t0; t < len; ++t) {
    float4 cv = PTGL(t);
    float2 kc = SKLL(t);
    ksum += kc.y;
    if (!act) eps = eL;
    bool inc = (lane != 0) && (m1 != 0.f);
    int d = inc ? (eL - eps) : 0;
    float m1s;
    if (__builtin_expect(d > 24, 0)) {
      a0 = ldexpf(a0, -d); a1 = ldexpf(a1, -d); a2 = ldexpf(a2, -d);
      a3 = ldexpf(a3, -d); a4 = ldexpf(a4, -d); a5 = ldexpf(a5, -d);
      a6 = ldexpf(a6, -d); a7 = ldexpf(a7, -d); a8 = ldexpf(a8, -d);
      eps += d; m1s = m1;
    } else {
      m1s = inc ? ldexpf(m1, d) : 0.f;
    }
    act = act || (m1s != 0.f);
    a8 = (a8 + a7) * kc.x;
    a7 = (a7 + a6 + (sk7 ? a5 : 0.f)) * cv.w;
    a6 = (a6 + a5) * kc.x;
    a5 = (a5 + a4 + (sk5 ? a3 : 0.f)) * cv.z;
    a4 = (a4 + a3) * kc.x;
    a3 = (a3 + a2 + (sk3 ? a1 : 0.f)) * cv.y;
    a2 = (a2 + a1) * kc.x;
    a1 = (a1 + a0 + (sk1 ? m1s : 0.f)) * cv.x;
    a0 = (a0 + m1s) * kc.x;
    if ((t & 7) == 0) RENORM();
    m1 = __shfl_up(a7, 1);
    eL = __shfl_up(eps, 1);
    if (lane == 0) m1 = 0.f;
  }

  // final reduce — all cross-lane via shfl (no LDS / no barrier)
  int last = 2 * tl;
  int kx = last >> 3, jx = last & 7;
  if (kx > 63) { kx = 63; jx = last - 504; }     // state 512 -> lane63 a8
  int ky = (last - 1) >> 3, jy = (last - 1) & 7;
  float vx = pick9(jx, a0, a1, a2, a3, a4, a5, a6, a7, a8);
  float vy = pick9(jy, a0, a1, a2, a3, a4, a5, a6, a7, a8);
  float sx = __shfl(vx, kx); int ex = __shfl(eps, kx);
  float sy = __shfl(vy, ky); int ey = __shfl(eps, ky);
  if (lane == 0) {
    int em = (ex > ey) ? ex : ey;
    float v = ldexpf(sx, ex - em) + ldexpf(sy, ey - em);
    float score = logf(v) + (float)em * LN2f - ksum;
    partial[n] = -score / (float)tl;
  }
#undef WAITC
#undef PTGL
#undef SKLL
#undef RENORM
#undef PAIR
}

// ---------------------------------------------------------------------------
// Kernel 3: mean over batch
// ---------------------------------------------------------------------------
__global__ void reduce_mean(const float* __restrict__ partial,
                            float* __restrict__ out, int B) {
  float v = 0.f;
  for (int i = threadIdx.x; i < B; i += 64) v += partial[i];
  #pragma unroll
  for (int off = 32; off > 0; off >>= 1) v += __shfl_down(v, off, 64);
  if (threadIdx.x == 0) out[0] = v / (float)B;
}

extern "C" void kernel_launch(void* const* d_in, const int* in_sizes, int n_in,
                              void* d_out, int out_size, void* d_ws, size_t ws_size,
                              hipStream_t stream) {
  const float* feat = (const float*)d_in[0];
  const float* W = (const float*)d_in[1];
  const float* bias = (const float*)d_in[2];
  const int* targets = (const int*)d_in[3];
  const int* in_len = (const int*)d_in[4];
  const int* tgt_len = (const int*)d_in[5];
  float* out = (float*)d_out;

  const int V = in_sizes[2];
  const int D = in_sizes[1] / V;
  const int B = in_sizes[4];
  const int T = in_sizes[0] / (B * D);
  const int S = in_sizes[3] / B;
  const int nrows = B * T;

  float* ptg = (float*)d_ws;                        // nrows*256 fp32 (64 MB)
  float* skb = ptg + (size_t)nrows * 256;           // nrows*2 fp32
  float* partial = skb + (size_t)nrows * 2;         // B fp32
  short* Wb = (short*)(partial + B);                // 64*D bf16
  const int CPB = (T + 127) / 128;                  // time-chunks per batch
  int* flags = (int*)((char*)Wb + (size_t)64 * D * sizeof(short));  // B*CPB

  hipMemsetAsync(flags, 0, (size_t)B * CPB * sizeof(int), stream);

  conv_w<<<(64 * D + 255) / 256, 256, 0, stream>>>(W, Wb, V, D);

  // grid = exactly 256 blocks: B consumers (resident first) + 224
  // persistent producers (1 block/CU; c-major chunk wavefront).
  int NPROD = 256 - B;
  const int NTILES = B * CPB;
  if (NPROD > NTILES) NPROD = NTILES;
  fused_gemm_star<<<dim3(B + NPROD), 256, 0, stream>>>(
      feat, Wb, bias, ptg, skb, flags, targets, in_len, tgt_len, partial,
      nrows, D, V, T, S, B, CPB);

  reduce_mean<<<1, 64, 0, stream>>>(partial, out, B);
}